// Round 2
// baseline (184.916 us; speedup 1.0000x reference)
//
#include <hip/hip_runtime.h>

// ImportancePooling: N=100000 nodes, K=32 neighbors, D=64 features.
// One wave per node; lane d owns feature d.
// Per-node (weights, neighbors) are wave-uniform -> v_readlane into SGPRs,
// so every gather is global_load_dword v, v_laneoff, s[row_base]:
// 1 dest VGPR per outstanding load, shared scalar base => ~32 loads in flight.

#define K_NBR 32
#define D_FEAT 64

__global__ __launch_bounds__(256) void ImportancePooling_28424093564958_kernel(
    const float* __restrict__ x,        // [N, 64]
    const int* __restrict__ neighbors,  // [N, 32]
    const float* __restrict__ weights,  // [N, 32]
    float* __restrict__ out,            // [N, 64]
    int N) {
  const int wave_id = (int)((blockIdx.x * blockDim.x + threadIdx.x) >> 6);
  const int lane = threadIdx.x & 63;
  if (wave_id >= N) return;

  // Merged header load: lanes 0..31 carry this node's weights (bit pattern),
  // lanes 32..63 carry its neighbor indices. One 128B-coalesced load per half.
  const long hbase = (long)wave_id * K_NBR;
  int packed;
  if (lane < K_NBR) {
    packed = __float_as_int(weights[hbase + lane]);
  } else {
    packed = neighbors[hbase + (lane - K_NBR)];
  }

  // K-loop: readlane pulls (wk, idx) into SGPRs (wave-uniform), the gather
  // address is scalar-base + lane*4. Fully unrolled: 32 independent loads.
  float acc = 0.0f;
  float wsum = 0.0f;
  #pragma unroll
  for (int k = 0; k < K_NBR; ++k) {
    const float wk = __int_as_float(__builtin_amdgcn_readlane(packed, k));
    const int idx = __builtin_amdgcn_readlane(packed, K_NBR + k);
    wsum += wk;
    acc += wk * x[(long)idx * D_FEAT + lane];
  }

  const float inv = (wsum > 0.0f) ? (1.0f / wsum) : 1.0f;
  out[(long)wave_id * D_FEAT + lane] = acc * inv;
}

extern "C" void kernel_launch(void* const* d_in, const int* in_sizes, int n_in,
                              void* d_out, int out_size, void* d_ws, size_t ws_size,
                              hipStream_t stream) {
  const float* x = (const float*)d_in[0];
  const int* neighbors = (const int*)d_in[1];
  const float* weights = (const float*)d_in[2];
  float* out = (float*)d_out;

  const int N = in_sizes[0] / D_FEAT;  // 100000
  const int block = 256;               // 4 waves/block
  const int grid = (N * 64 + block - 1) / block;

  ImportancePooling_28424093564958_kernel<<<grid, block, 0, stream>>>(
      x, neighbors, weights, out, N);
}

// Round 3
// 136.734 us; speedup vs baseline: 1.3524x; 1.3524x over previous
//
#include <hip/hip_runtime.h>
#include <hip/hip_fp16.h>

// ImportancePooling: N=100000 nodes, K=32 neighbors, D=64 features.
// The gather is L2-miss-path throughput-bound (x=25.6MB >> 4MiB/XCD L2,
// uniform-random neighbors -> 352MB miss traffic @ ~3.4TB/s). Lever: bytes.
// Pass 1 stages x as fp16 into d_ws (halves gather bytes AND footprint);
// Pass 2 gathers fp16 rows, computes in fp32.

#define K_NBR 32
#define D_FEAT 64

__global__ __launch_bounds__(256) void ImportancePooling_28424093564958_convert(
    const float* __restrict__ x, __half* __restrict__ xh, int total2) {
  const int i = blockIdx.x * blockDim.x + threadIdx.x;
  if (i < total2) {
    const float2 v = ((const float2*)x)[i];
    ((__half2*)xh)[i] = __floats2half2_rn(v.x, v.y);
  }
}

__global__ __launch_bounds__(256) void ImportancePooling_28424093564958_kernel(
    const __half* __restrict__ xh,      // [N, 64] staged fp16
    const int* __restrict__ neighbors,  // [N, 32]
    const float* __restrict__ weights,  // [N, 32]
    float* __restrict__ out,            // [N, 64]
    int N) {
  const int wave_id = (int)((blockIdx.x * blockDim.x + threadIdx.x) >> 6);
  const int lane = threadIdx.x & 63;
  if (wave_id >= N) return;

  // Merged header: lanes 0..31 carry weights (bits), lanes 32..63 neighbor ids.
  const long hbase = (long)wave_id * K_NBR;
  int packed;
  if (lane < K_NBR) {
    packed = __float_as_int(weights[hbase + lane]);
  } else {
    packed = neighbors[hbase + (lane - K_NBR)];
  }

  float acc = 0.0f;
  float wsum = 0.0f;
  #pragma unroll
  for (int k = 0; k < K_NBR; ++k) {
    const float wk = __int_as_float(__builtin_amdgcn_readlane(packed, k));
    const int idx = __builtin_amdgcn_readlane(packed, K_NBR + k);
    wsum += wk;
    acc += wk * __half2float(xh[(long)idx * D_FEAT + lane]);
  }

  const float inv = (wsum > 0.0f) ? (1.0f / wsum) : 1.0f;
  out[(long)wave_id * D_FEAT + lane] = acc * inv;
}

// Fallback (ws too small): direct fp32 gather, identical math.
__global__ __launch_bounds__(256) void ImportancePooling_28424093564958_f32(
    const float* __restrict__ x, const int* __restrict__ neighbors,
    const float* __restrict__ weights, float* __restrict__ out, int N) {
  const int wave_id = (int)((blockIdx.x * blockDim.x + threadIdx.x) >> 6);
  const int lane = threadIdx.x & 63;
  if (wave_id >= N) return;
  const long hbase = (long)wave_id * K_NBR;
  int packed;
  if (lane < K_NBR) {
    packed = __float_as_int(weights[hbase + lane]);
  } else {
    packed = neighbors[hbase + (lane - K_NBR)];
  }
  float acc = 0.0f, wsum = 0.0f;
  #pragma unroll
  for (int k = 0; k < K_NBR; ++k) {
    const float wk = __int_as_float(__builtin_amdgcn_readlane(packed, k));
    const int idx = __builtin_amdgcn_readlane(packed, K_NBR + k);
    wsum += wk;
    acc += wk * x[(long)idx * D_FEAT + lane];
  }
  const float inv = (wsum > 0.0f) ? (1.0f / wsum) : 1.0f;
  out[(long)wave_id * D_FEAT + lane] = acc * inv;
}

extern "C" void kernel_launch(void* const* d_in, const int* in_sizes, int n_in,
                              void* d_out, int out_size, void* d_ws, size_t ws_size,
                              hipStream_t stream) {
  const float* x = (const float*)d_in[0];
  const int* neighbors = (const int*)d_in[1];
  const float* weights = (const float*)d_in[2];
  float* out = (float*)d_out;

  const int N = in_sizes[0] / D_FEAT;  // 100000
  const int block = 256;               // 4 waves/block
  const int grid = (N * 64 + block - 1) / block;

  const size_t xh_bytes = (size_t)N * D_FEAT * sizeof(__half);
  if (ws_size >= xh_bytes) {
    __half* xh = (__half*)d_ws;
    const int total2 = N * D_FEAT / 2;
    ImportancePooling_28424093564958_convert<<<(total2 + 255) / 256, 256, 0, stream>>>(
        x, xh, total2);
    ImportancePooling_28424093564958_kernel<<<grid, block, 0, stream>>>(
        xh, neighbors, weights, out, N);
  } else {
    ImportancePooling_28424093564958_f32<<<grid, block, 0, stream>>>(
        x, neighbors, weights, out, N);
  }
}

// Round 4
// 135.594 us; speedup vs baseline: 1.3637x; 1.0084x over previous
//
#include <hip/hip_runtime.h>
#include <hip/hip_fp16.h>

// ImportancePooling: N=100000, K=32, D=64.
// Staged-fp16 gather (round-3 win) + 2-nodes-per-wave half2 packing:
//  - lanes 0..31 = node A, 32..63 = node B; each lane owns 2 features (half2)
//  - one global_load_dword serves two neighbor rows (256B/instr)
//  - ds_bpermute broadcasts (w,idx) per half -> off the VALU pipe
//  - v_fma_mix (via fmaf+__low2float) folds the fp16->fp32 cvt into the fma

#define K_NBR 32
#define D_FEAT 64

__global__ __launch_bounds__(256) void ImportancePooling_28424093564958_convert(
    const float4* __restrict__ x4, uint2* __restrict__ xh4, int n4) {
  const int i = blockIdx.x * blockDim.x + threadIdx.x;
  if (i < n4) {
    const float4 v = x4[i];
    const __half2 a = __floats2half2_rn(v.x, v.y);
    const __half2 b = __floats2half2_rn(v.z, v.w);
    uint2 u;
    u.x = *(const unsigned int*)&a;
    u.y = *(const unsigned int*)&b;
    xh4[i] = u;
  }
}

__global__ __launch_bounds__(256) void ImportancePooling_28424093564958_kernel(
    const __half2* __restrict__ xh2,    // [N, 32] half2 view of staged fp16 x
    const int* __restrict__ neighbors,  // [N, 32]
    const float* __restrict__ weights,  // [N, 32]
    float2* __restrict__ out2,          // [N, 32] float2 view of out
    int Nw) {                           // Nw = N/2 (waves)
  const int wave_id = (int)((blockIdx.x * blockDim.x + threadIdx.x) >> 6);
  const int lane = threadIdx.x & 63;
  if (wave_id >= Nw) return;

  // Header: lanes 0..31 = node A's 32 (w, idx), lanes 32..63 = node B's.
  // weights/neighbors rows of consecutive nodes are contiguous -> coalesced.
  const long hbase = (long)wave_id * 64;
  const int w_bits = __float_as_int(weights[hbase + lane]);
  const int nb = neighbors[hbase + lane];

  // Per-half wsum: xor offsets <=16 never cross the 32-lane half boundary.
  float wsum = __int_as_float(w_bits);
  #pragma unroll
  for (int off = 16; off >= 1; off >>= 1) wsum += __shfl_xor(wsum, off, 64);
  const float inv = (wsum > 0.0f) ? (1.0f / wsum) : 1.0f;

  const int vbase = (lane & 32) << 2;  // bpermute byte base: 0 or 128
  const int sub = lane & 31;           // half2 column within the row

  float accx = 0.0f, accy = 0.0f;
  #pragma unroll
  for (int k = 0; k < K_NBR; ++k) {
    const int wk_b = __builtin_amdgcn_ds_bpermute(vbase + 4 * k, w_bits);
    const int idx = __builtin_amdgcn_ds_bpermute(vbase + 4 * k, nb);
    const float wk = __int_as_float(wk_b);
    const __half2 h = xh2[(long)idx * (D_FEAT / 2) + sub];
    accx = fmaf(wk, __low2float(h), accx);   // v_fma_mix_f32
    accy = fmaf(wk, __high2float(h), accy);
  }

  float2 o;
  o.x = accx * inv;
  o.y = accy * inv;
  // out2 row for node 2w+half starts at (2w+half)*32 -> index = w*64 + lane.
  out2[hbase + lane] = o;
}

// Fallback (ws too small): direct fp32 gather, one node per wave.
__global__ __launch_bounds__(256) void ImportancePooling_28424093564958_f32(
    const float* __restrict__ x, const int* __restrict__ neighbors,
    const float* __restrict__ weights, float* __restrict__ out, int N) {
  const int wave_id = (int)((blockIdx.x * blockDim.x + threadIdx.x) >> 6);
  const int lane = threadIdx.x & 63;
  if (wave_id >= N) return;
  const long hbase = (long)wave_id * K_NBR;
  int packed;
  if (lane < K_NBR) {
    packed = __float_as_int(weights[hbase + lane]);
  } else {
    packed = neighbors[hbase + (lane - K_NBR)];
  }
  float acc = 0.0f, wsum = 0.0f;
  #pragma unroll
  for (int k = 0; k < K_NBR; ++k) {
    const float wk = __int_as_float(__builtin_amdgcn_readlane(packed, k));
    const int idx = __builtin_amdgcn_readlane(packed, K_NBR + k);
    wsum += wk;
    acc += wk * x[(long)idx * D_FEAT + lane];
  }
  const float inv = (wsum > 0.0f) ? (1.0f / wsum) : 1.0f;
  out[(long)wave_id * D_FEAT + lane] = acc * inv;
}

extern "C" void kernel_launch(void* const* d_in, const int* in_sizes, int n_in,
                              void* d_out, int out_size, void* d_ws, size_t ws_size,
                              hipStream_t stream) {
  const float* x = (const float*)d_in[0];
  const int* neighbors = (const int*)d_in[1];
  const float* weights = (const float*)d_in[2];

  const int N = in_sizes[0] / D_FEAT;  // 100000
  const size_t xh_bytes = (size_t)N * D_FEAT * sizeof(__half);

  if (ws_size >= xh_bytes && (N % 2) == 0) {
    const int n4 = N * D_FEAT / 4;
    ImportancePooling_28424093564958_convert<<<(n4 + 255) / 256, 256, 0, stream>>>(
        (const float4*)x, (uint2*)d_ws, n4);

    const int Nw = N / 2;
    const int block = 256;  // 4 waves/block
    const int grid = (Nw * 64 + block - 1) / block;
    ImportancePooling_28424093564958_kernel<<<grid, block, 0, stream>>>(
        (const __half2*)d_ws, neighbors, weights, (float2*)d_out, Nw);
  } else {
    const int block = 256;
    const int grid = (N * 64 + block - 1) / block;
    ImportancePooling_28424093564958_f32<<<grid, block, 0, stream>>>(
        x, neighbors, weights, (float*)d_out, N);
  }
}